// Round 8
// baseline (563.211 us; speedup 1.0000x reference)
//
#include <hip/hip_runtime.h>
#include <math.h>

#define N 8192
#define D 64
#define E_K 262144
#define E_HK 262144
#define NEDGE (E_K + E_HK)   // 524288 = 2^19 -> edge idx fits 19 bits
#define CAP 256              // slots/row; degree mean 128, sigma ~11
#define TAB_N 2048           // F(s) table over s in [-1,1]

__device__ inline float fast_tanh(float x) {
  x = fminf(15.f, fmaxf(-15.f, x));
  float e = __expf(2.f * x);
  return (e - 1.f) * __builtin_amdgcn_rcpf(e + 1.f);
}

__device__ inline float wave_reduce(float v) {
  #pragma unroll
  for (int off = 32; off > 0; off >>= 1) v += __shfl_xor(v, off);
  return v;
}

// ---- kernel 1: prep (Knorm, g, Om, Tab) + edge index scatter ----
// entry = (other << 19) | edge_idx   (other<8192: 13 bits; edge<2^19)
__global__ __launch_bounds__(256) void prep_scatter_kernel(
    const float* __restrict__ state_K, const float* __restrict__ state_H,
    const float* __restrict__ omega,
    const int* __restrict__ ind_HK, const int* __restrict__ ind_K,
    const float* __restrict__ w1, const float* __restrict__ b1,
    const float* __restrict__ w2,
    float* __restrict__ Knorm, float* __restrict__ g, float* __restrict__ Om,
    float* __restrict__ Tab, int* __restrict__ cursor,
    unsigned* __restrict__ entries) {
  int b = blockIdx.x;
  if (b < 2048) {                      // ---- scatter: one thread per edge
    int t = b * 256 + threadIdx.x;     // t = global edge index (HK then K)
    int2 e = (t < E_HK) ? ((const int2*)ind_HK)[t]
                        : ((const int2*)ind_K)[t - E_HK];
    unsigned i = (unsigned)e.x, j = (unsigned)e.y;
    int s0 = atomicAdd(&cursor[i], 1);
    if (s0 < CAP) entries[i * CAP + s0] = (j << 19) | (unsigned)t;
    int s1 = atomicAdd(&cursor[j], 1);
    if (s1 < CAP) entries[j * CAP + s1] = (i << 19) | (unsigned)t;
  } else if (b < 4096) {               // ---- prep: 4 rows per block
    int lane = threadIdx.x & 63;
    int row  = (b - 2048) * 4 + (threadIdx.x >> 6);
    float v  = state_K[row * D + lane];
    float ss = wave_reduce(v * v);
    Knorm[row * D + lane] = v * __builtin_amdgcn_rcpf(sqrtf(ss));
    if (lane == 0) g[row] = fast_tanh(state_H[row]);
  } else if (b == 4096) {              // ---- skew-omega (one block)
    for (int t = threadIdx.x; t < D * D; t += 256) {
      int a = t >> 6, c = t & 63;
      Om[t] = 0.5f * (omega[a * D + c] - omega[c * D + a]);
    }
  } else {                             // ---- F(s) table: wave per point
    int lane = threadIdx.x & 63;
    int p = (b - 4097) * 4 + (threadIdx.x >> 6);
    if (p <= TAB_N) {
      float s = (float)p * (2.0f / TAB_N) - 1.0f;
      float t = fast_tanh(s * w1[lane] + b1[lane]) * w2[lane];
      t = wave_reduce(t);
      if (lane == 0) Tab[p] = t;
    }
  }
}

// ---- kernel 2: matvec (blocks [0,N)) fused with per-edge coeff ----------
// (blocks [N, N+NEDGE/4)): HBM-stream and L2/DS work co-scheduled.
__global__ __launch_bounds__(256) void matvec_coeff_kernel(
    const float* __restrict__ W_H, const float* __restrict__ g,
    const float* __restrict__ state_H, const float* __restrict__ Knorm,
    const float* __restrict__ Tab,
    const int* __restrict__ ind_HK, const int* __restrict__ ind_K,
    float* __restrict__ f_H, float* __restrict__ coeff) {
  int b    = blockIdx.x;
  int lane = threadIdx.x & 63;
  int wv   = threadIdx.x >> 6;
  __shared__ float sbuf[4];
  if (b < N) {                         // ---- matvec row
    int row = b;
    const float4* Wrow = reinterpret_cast<const float4*>(W_H + (size_t)row * N);
    const float4* g4   = reinterpret_cast<const float4*>(g);
    float acc = 0.0f;
    #pragma unroll
    for (int c = threadIdx.x; c < N / 4; c += 256) {
      float4 w = Wrow[c];
      float4 gg = g4[c];
      acc += w.x * gg.x + w.y * gg.y + w.z * gg.z + w.w * gg.w;
    }
    acc = wave_reduce(acc);
    if (lane == 0) sbuf[wv] = acc;
    __syncthreads();
    if (threadIdx.x == 0)
      f_H[row] = -state_H[row] + sbuf[0] + sbuf[1] + sbuf[2] + sbuf[3];
  } else {                             // ---- coeff: 1 wave per edge
    int wid = (b - N) * 4 + wv;        // wid < NEDGE by grid construction
    int2 e = (wid < E_HK) ? ((const int2*)ind_HK)[wid]
                          : ((const int2*)ind_K)[wid - E_HK];
    float kp = Knorm[e.x * D + lane];
    float kq = Knorm[e.y * D + lane];
    float s = wave_reduce(kp * kq);
    float c = s;                       // HK edge stores the Gram dot
    if (wid >= E_HK) {                 // K edge: dE/ds via table lerp
      float x = fminf(fmaxf((s + 1.0f) * (TAB_N * 0.5f), 0.0f), (float)TAB_N);
      int   i  = min((int)x, TAB_N - 1);
      float fr = x - (float)i;
      c = Tab[i] + (Tab[i + 1] - Tab[i]) * fr;
    }
    if (lane == 0) coeff[wid] = c;
  }
}

// ---- kernel 3: gather + finalize — no reduces, no mid-kernel barrier -----
// Wave wv owns slots {wv, wv+4, wv+8, ...}: lane l pre-loads slot 4l+wv,
// then entries are broadcast per-k via __shfl. Per entry: 3 shfl + one
// coalesced 256B Knorm load + 3 FMA.
__global__ __launch_bounds__(256) void gather_kernel(
    const float* __restrict__ Knorm, const float* __restrict__ g,
    const float* __restrict__ Om, const float* __restrict__ coeff,
    const int* __restrict__ cursor, const unsigned* __restrict__ entries,
    float* __restrict__ f_H, float* __restrict__ f_K) {
  int row  = blockIdx.x;
  int lane = threadIdx.x & 63;
  int wv   = threadIdx.x >> 6;
  float kr = Knorm[row * D + lane];
  float gr = g[row];
  int len  = min(cursor[row], CAP);

  int slot = lane * 4 + wv;
  unsigned myent = (unsigned)E_HK;     // pad: K-type (eidx=E_HK), other=0
  float myc = 0.f, myg = 0.f;          // c=0 -> contributes nothing
  if (slot < len) {
    myent = entries[(size_t)row * CAP + slot];
    myc   = coeff[myent & 0x7FFFFu];
    myg   = g[myent >> 19];
  }
  int nl = (len > wv) ? min(64, (len - wv + 3) >> 2) : 0;

  float acc = 0.f, sH = 0.f;
  for (int k = 0; k < nl; k += 4) {
    #pragma unroll
    for (int u = 0; u < 4; ++u) {      // overshoot lanes hold zero pads
      unsigned ent = (unsigned)__shfl((int)myent, k + u);
      float c  = __shfl(myc, k + u);
      float go = __shfl(myg, k + u);
      unsigned oth = ent >> 19;
      bool hk = (ent & 0x7FFFFu) < (unsigned)E_HK;
      float ko = Knorm[oth * D + lane];
      acc += (hk ? (-gr * go * 0.5f) : c) * ko;
      sH  += hk ? c * go : 0.f;
    }
  }

  __shared__ float sAcc[4][D];
  __shared__ float sHs[4];
  sAcc[wv][lane] = acc;
  if (lane == 0) sHs[wv] = sH;
  __syncthreads();
  if (wv == 0) {
    float tot = sAcc[0][lane] + sAcc[1][lane] + sAcc[2][lane] + sAcc[3][lane];
    float rd = wave_reduce(kr * tot);            // rowdot(K, A)
    float krot = 0.f;
    #pragma unroll
    for (int d = 0; d < D; ++d)
      krot += __shfl(kr, d) * Om[d * D + lane];
    f_K[row * D + lane] = -tot + kr * rd + krot;
    if (lane == 0)
      f_H[row] += (sHs[0] + sHs[1] + sHs[2] + sHs[3]) * 0.5f;
  }
}

extern "C" void kernel_launch(void* const* d_in, const int* in_sizes, int n_in,
                              void* d_out, int out_size, void* d_ws, size_t ws_size,
                              hipStream_t stream) {
  const float* state_H = (const float*)d_in[0];
  const float* state_K = (const float*)d_in[1];
  const float* W_H     = (const float*)d_in[2];
  const float* omega   = (const float*)d_in[3];
  const float* w1      = (const float*)d_in[4];
  const float* b1      = (const float*)d_in[5];
  const float* w2      = (const float*)d_in[6];
  const int*   ind_K   = (const int*)d_in[7];
  const int*   ind_HK  = (const int*)d_in[8];

  float* f_H = (float*)d_out;       // N
  float* f_K = (float*)d_out + N;   // N*D

  char* ws = (char*)d_ws;
  unsigned* entries = (unsigned*)ws;     ws += (size_t)N * CAP * sizeof(unsigned); // 8 MB
  float* Knorm  = (float*)ws;            ws += (size_t)N * D * sizeof(float);      // 2 MB
  float* coeff  = (float*)ws;            ws += (size_t)NEDGE * sizeof(float);      // 2 MB
  float* g      = (float*)ws;            ws += N * sizeof(float);
  float* Om     = (float*)ws;            ws += D * D * sizeof(float);
  float* Tab    = (float*)ws;            ws += (TAB_N + 1) * sizeof(float);
  int*   cursor = (int*)ws;

  hipMemsetAsync(cursor, 0, N * sizeof(int), stream);
  prep_scatter_kernel<<<4097 + 513, 256, 0, stream>>>(
      state_K, state_H, omega, ind_HK, ind_K, w1, b1, w2,
      Knorm, g, Om, Tab, cursor, entries);
  matvec_coeff_kernel<<<N + NEDGE / 4, 256, 0, stream>>>(
      W_H, g, state_H, Knorm, Tab, ind_HK, ind_K, f_H, coeff);
  gather_kernel<<<N, 256, 0, stream>>>(Knorm, g, Om, coeff, cursor, entries,
                                       f_H, f_K);
}

// Round 10
// 514.423 us; speedup vs baseline: 1.0948x; 1.0948x over previous
//
#include <hip/hip_runtime.h>
#include <math.h>

#define N 8192
#define D 64
#define E_K 262144
#define E_HK 262144
#define NEDGE (E_K + E_HK)   // 524288 = 2^19 -> edge idx fits 19 bits
#define CAP 256              // slots/row; degree mean 128, sigma ~11
#define TAB_N 2048           // F(s) table over s in [-1,1]

__device__ inline float fast_tanh(float x) {
  x = fminf(15.f, fmaxf(-15.f, x));
  float e = __expf(2.f * x);
  return (e - 1.f) * __builtin_amdgcn_rcpf(e + 1.f);
}

__device__ inline float wave_reduce(float v) {
  #pragma unroll
  for (int off = 32; off > 0; off >>= 1) v += __shfl_xor(v, off);
  return v;
}

// ---- kernel 1: prep (Knorm, g, Om, Tab) + edge index scatter ----
// entry = (other << 19) | edge_idx
__global__ __launch_bounds__(256) void prep_scatter_kernel(
    const float* __restrict__ state_K, const float* __restrict__ state_H,
    const float* __restrict__ omega,
    const int* __restrict__ ind_HK, const int* __restrict__ ind_K,
    const float* __restrict__ w1, const float* __restrict__ b1,
    const float* __restrict__ w2,
    float* __restrict__ Knorm, float* __restrict__ g, float* __restrict__ Om,
    float* __restrict__ Tab, int* __restrict__ cursor,
    unsigned* __restrict__ entries) {
  int b = blockIdx.x;
  if (b < 2048) {                      // ---- scatter: one thread per edge
    int t = b * 256 + threadIdx.x;     // global edge index (HK then K)
    int2 e = (t < E_HK) ? ((const int2*)ind_HK)[t]
                        : ((const int2*)ind_K)[t - E_HK];
    unsigned i = (unsigned)e.x, j = (unsigned)e.y;
    int s0 = atomicAdd(&cursor[i], 1);
    if (s0 < CAP) entries[i * CAP + s0] = (j << 19) | (unsigned)t;
    int s1 = atomicAdd(&cursor[j], 1);
    if (s1 < CAP) entries[j * CAP + s1] = (i << 19) | (unsigned)t;
  } else if (b < 4096) {               // ---- prep: 4 rows per block
    int lane = threadIdx.x & 63;
    int row  = (b - 2048) * 4 + (threadIdx.x >> 6);
    float v  = state_K[row * D + lane];
    float ss = wave_reduce(v * v);
    Knorm[row * D + lane] = v * __builtin_amdgcn_rcpf(sqrtf(ss));
    if (lane == 0) g[row] = fast_tanh(state_H[row]);
  } else if (b == 4096) {              // ---- skew-omega (one block)
    for (int t = threadIdx.x; t < D * D; t += 256) {
      int a = t >> 6, c = t & 63;
      Om[t] = 0.5f * (omega[a * D + c] - omega[c * D + a]);
    }
  } else {                             // ---- F(s) table: wave per point
    int lane = threadIdx.x & 63;
    int p = (b - 4097) * 4 + (threadIdx.x >> 6);
    if (p <= TAB_N) {
      float s = (float)p * (2.0f / TAB_N) - 1.0f;
      float t = fast_tanh(s * w1[lane] + b1[lane]) * w2[lane];
      t = wave_reduce(t);
      if (lane == 0) Tab[p] = t;
    }
  }
}

// ---- kernel 2: coeff — ONE THREAD PER EDGE, no cross-lane ops ----------
__global__ __launch_bounds__(256) void coeff_kernel(
    const float* __restrict__ Knorm, const float* __restrict__ Tab,
    const int* __restrict__ ind_HK, const int* __restrict__ ind_K,
    float* __restrict__ coeff) {
  int t = blockIdx.x * 256 + threadIdx.x;          // t < NEDGE
  int2 e = (t < E_HK) ? ((const int2*)ind_HK)[t]
                      : ((const int2*)ind_K)[t - E_HK];
  const float4* rp = reinterpret_cast<const float4*>(Knorm + (size_t)e.x * D);
  const float4* rq = reinterpret_cast<const float4*>(Knorm + (size_t)e.y * D);
  float s = 0.f;
  #pragma unroll
  for (int d4 = 0; d4 < 16; ++d4) {
    float4 a = rp[d4], b = rq[d4];
    s += a.x * b.x + a.y * b.y + a.z * b.z + a.w * b.w;
  }
  float c = s;                         // HK edge stores the Gram dot
  if (t >= E_HK) {                     // K edge: dE/ds via table lerp
    float x = fminf(fmaxf((s + 1.0f) * (TAB_N * 0.5f), 0.0f), (float)TAB_N);
    int   i  = min((int)x, TAB_N - 1);
    float fr = x - (float)i;
    c = Tab[i] + (Tab[i + 1] - Tab[i]) * fr;
  }
  coeff[t] = c;
}

// ---- kernel 3: matvec — ONE ROW PER WAVE, no LDS, no barriers ----------
__global__ __launch_bounds__(256) void matvec_kernel(
    const float* __restrict__ W_H, const float* __restrict__ g,
    const float* __restrict__ state_H, float* __restrict__ f_H) {
  int lane = threadIdx.x & 63;
  int row  = blockIdx.x * 4 + (threadIdx.x >> 6);
  const float4* Wrow = reinterpret_cast<const float4*>(W_H + (size_t)row * N);
  const float4* g4   = reinterpret_cast<const float4*>(g);
  float acc = 0.f;
  #pragma unroll 4
  for (int o = 0; o < 32; o += 8) {    // 32 float4 per lane, 8-deep MLP
    #pragma unroll
    for (int k = 0; k < 8; ++k) {
      float4 w  = Wrow[lane + (o + k) * 64];
      float4 gg = g4[lane + (o + k) * 64];
      acc += w.x * gg.x + w.y * gg.y + w.z * gg.z + w.w * gg.w;
    }
  }
  acc = wave_reduce(acc);
  if (lane == 0) f_H[row] = -state_H[row] + acc;
}

// ---- kernel 4: gather + finalize — no reduces, no mid-kernel barrier ----
__global__ __launch_bounds__(256) void gather_kernel(
    const float* __restrict__ Knorm, const float* __restrict__ g,
    const float* __restrict__ Om, const float* __restrict__ coeff,
    const int* __restrict__ cursor, const unsigned* __restrict__ entries,
    float* __restrict__ f_H, float* __restrict__ f_K) {
  int row  = blockIdx.x;
  int lane = threadIdx.x & 63;
  int wv   = threadIdx.x >> 6;
  float kr = Knorm[row * D + lane];
  float gr = g[row];
  int len  = min(cursor[row], CAP);

  int slot = lane * 4 + wv;
  unsigned myent = (unsigned)E_HK;     // pad: K-type, other=0, c=0
  float myc = 0.f, myg = 0.f;
  if (slot < len) {
    myent = entries[(size_t)row * CAP + slot];
    myc   = coeff[myent & 0x7FFFFu];
    myg   = g[myent >> 19];
  }
  int nl = (len > wv) ? min(64, (len - wv + 3) >> 2) : 0;

  float acc = 0.f, sH = 0.f;
  for (int k = 0; k < nl; k += 4) {
    #pragma unroll
    for (int u = 0; u < 4; ++u) {      // overshoot lanes hold zero pads
      unsigned ent = (unsigned)__shfl((int)myent, k + u);
      float c  = __shfl(myc, k + u);
      float go = __shfl(myg, k + u);
      unsigned oth = ent >> 19;
      bool hk = (ent & 0x7FFFFu) < (unsigned)E_HK;
      float ko = Knorm[oth * D + lane];
      acc += (hk ? (-gr * go * 0.5f) : c) * ko;
      sH  += hk ? c * go : 0.f;
    }
  }

  __shared__ float sAcc[4][D];
  __shared__ float sHs[4];
  sAcc[wv][lane] = acc;
  if (lane == 0) sHs[wv] = sH;
  __syncthreads();
  if (wv == 0) {
    float tot = sAcc[0][lane] + sAcc[1][lane] + sAcc[2][lane] + sAcc[3][lane];
    float rd = wave_reduce(kr * tot);            // rowdot(K, A)
    float krot = 0.f;
    #pragma unroll
    for (int d = 0; d < D; ++d)
      krot += __shfl(kr, d) * Om[d * D + lane];
    f_K[row * D + lane] = -tot + kr * rd + krot;
    if (lane == 0)
      f_H[row] += (sHs[0] + sHs[1] + sHs[2] + sHs[3]) * 0.5f;
  }
}

extern "C" void kernel_launch(void* const* d_in, const int* in_sizes, int n_in,
                              void* d_out, int out_size, void* d_ws, size_t ws_size,
                              hipStream_t stream) {
  const float* state_H = (const float*)d_in[0];
  const float* state_K = (const float*)d_in[1];
  const float* W_H     = (const float*)d_in[2];
  const float* omega   = (const float*)d_in[3];
  const float* w1      = (const float*)d_in[4];
  const float* b1      = (const float*)d_in[5];
  const float* w2      = (const float*)d_in[6];
  const int*   ind_K   = (const int*)d_in[7];
  const int*   ind_HK  = (const int*)d_in[8];

  float* f_H = (float*)d_out;       // N
  float* f_K = (float*)d_out + N;   // N*D

  char* ws = (char*)d_ws;
  unsigned* entries = (unsigned*)ws;     ws += (size_t)N * CAP * sizeof(unsigned); // 8 MB
  float* Knorm  = (float*)ws;            ws += (size_t)N * D * sizeof(float);      // 2 MB
  float* coeff  = (float*)ws;            ws += (size_t)NEDGE * sizeof(float);      // 2 MB
  float* g      = (float*)ws;            ws += N * sizeof(float);
  float* Om     = (float*)ws;            ws += D * D * sizeof(float);
  float* Tab    = (float*)ws;            ws += (TAB_N + 1) * sizeof(float);
  int*   cursor = (int*)ws;

  hipMemsetAsync(cursor, 0, N * sizeof(int), stream);
  prep_scatter_kernel<<<4097 + 513, 256, 0, stream>>>(
      state_K, state_H, omega, ind_HK, ind_K, w1, b1, w2,
      Knorm, g, Om, Tab, cursor, entries);
  coeff_kernel<<<NEDGE / 256, 256, 0, stream>>>(Knorm, Tab, ind_HK, ind_K,
                                                coeff);
  matvec_kernel<<<N / 4, 256, 0, stream>>>(W_H, g, state_H, f_H);
  gather_kernel<<<N, 256, 0, stream>>>(Knorm, g, Om, coeff, cursor, entries,
                                       f_H, f_K);
}